// Round 2
// baseline (1320.712 us; speedup 1.0000x reference)
//
#include <hip/hip_runtime.h>

#define NN 100000
#define NE 1000000
#define DIN 32
#define HD 64
#define DOUT 8
#define BN_EPS 1e-5f

// ---------------- degree (in-degree of dst) ----------------
__global__ void deg_kernel(const int* __restrict__ ei, float* __restrict__ deg, int nE) {
    int e = blockIdx.x * 256 + threadIdx.x;
    if (e < nE) {
        int d = ei[nE + e];   // dst row of edge_index
        atomicAdd(&deg[d], 1.0f);
    }
}

__global__ void dinv_kernel(float* __restrict__ deg, int n) {
    int i = blockIdx.x * 256 + threadIdx.x;
    if (i < n) deg[i] = rsqrtf(deg[i] + 1.0f);   // in-place: deg -> dinv
}

__global__ void edge_norm_kernel(const int* __restrict__ ei, const float* __restrict__ dinv,
                                 float* __restrict__ en, int nE) {
    int e = blockIdx.x * 256 + threadIdx.x;
    if (e < nE) {
        int s = ei[e];
        int d = ei[nE + e];
        en[e] = dinv[s] * dinv[d];
    }
}

// ---------------- GEMM: m = x @ W1  (32 -> 64), no BN on input ----------------
__global__ void gemm_in(const float* __restrict__ x, const float* __restrict__ W,
                        float* __restrict__ m, int n) {
    __shared__ float Ws[DIN * HD];   // 8 KB
    int tid = threadIdx.x;
    for (int i = tid; i < DIN * HD; i += 256) Ws[i] = W[i];
    __syncthreads();
    int f = tid & 63;
    int w = tid >> 6;
    for (int j = 0; j < 8; ++j) {
        int row = blockIdx.x * 32 + j * 4 + w;
        if (row >= n) return;
        const float* xr = x + (size_t)row * DIN;
        float acc = 0.f;
#pragma unroll
        for (int k = 0; k < DIN; ++k) acc = fmaf(xr[k], Ws[k * HD + f], acc);
        m[(size_t)row * HD + f] = acc;
    }
}

// ---------------- GEMM with fused BN on input: m = (h*scale+shift) @ W (64 -> 64) ----------------
__global__ void gemm_hid(const float* __restrict__ h, const float* __restrict__ W,
                         const float* __restrict__ stats, float* __restrict__ m, int n) {
    __shared__ float Ws[HD * HD];   // 16 KB
    __shared__ float sc[HD], sh[HD];
    int tid = threadIdx.x;
    for (int i = tid; i < HD * HD; i += 256) Ws[i] = W[i];
    if (tid < HD) { sc[tid] = stats[128 + tid]; sh[tid] = stats[192 + tid]; }
    __syncthreads();
    int f = tid & 63;
    int w = tid >> 6;
    for (int j = 0; j < 8; ++j) {
        int row = blockIdx.x * 32 + j * 4 + w;
        if (row >= n) return;
        const float* hr = h + (size_t)row * HD;
        float acc = 0.f;
#pragma unroll
        for (int k = 0; k < HD; ++k) {
            float v = fmaf(hr[k], sc[k], sh[k]);
            acc = fmaf(v, Ws[k * HD + f], acc);
        }
        m[(size_t)row * HD + f] = acc;
    }
}

// ---------------- agg init: agg = dinv^2 * m + b ----------------
__global__ void init_agg(const float* __restrict__ m, const float* __restrict__ dinv,
                         const float* __restrict__ b, float* __restrict__ agg, int total) {
    int idx = blockIdx.x * 256 + threadIdx.x;
    if (idx < total) {
        int i = idx >> 6, f = idx & 63;
        float di = dinv[i];
        agg[idx] = di * di * m[idx] + b[f];
    }
}

// ---------------- edge scatter: agg[dst] += en * m[src], one wave per edge ----------------
__global__ void scatter_kernel(const int* __restrict__ ei, const float* __restrict__ en,
                               const float* __restrict__ m, float* __restrict__ agg, int nE) {
    int lane = threadIdx.x & 63;
    int wid = (blockIdx.x * blockDim.x + threadIdx.x) >> 6;
    int nw = (gridDim.x * blockDim.x) >> 6;
    for (int e = wid; e < nE; e += nw) {
        int s = ei[e];
        int d = ei[nE + e];
        float w = en[e];
        atomicAdd(&agg[(size_t)d * HD + lane], w * m[(size_t)s * HD + lane]);
    }
}

// ---------------- ReLU in place + per-feature sum / sumsq ----------------
__global__ void relu_stats(float* __restrict__ h, float* __restrict__ stats, int total) {
    int tid = threadIdx.x;
    int f = tid & 63;
    float s = 0.f, s2 = 0.f;
    for (int idx = blockIdx.x * blockDim.x + tid; idx < total; idx += gridDim.x * blockDim.x) {
        float v = fmaxf(h[idx], 0.f);
        h[idx] = v;
        s += v;
        s2 += v * v;
    }
    __shared__ float ls[256], ls2[256];
    ls[tid] = s; ls2[tid] = s2;
    __syncthreads();
    if (tid < 64) {
        s = ls[tid] + ls[tid + 64] + ls[tid + 128] + ls[tid + 192];
        s2 = ls2[tid] + ls2[tid + 64] + ls2[tid + 128] + ls2[tid + 192];
        atomicAdd(&stats[f], s);
        atomicAdd(&stats[64 + f], s2);
    }
}

// ---------------- BN finalize: scale/shift ----------------
__global__ void bn_finalize(float* __restrict__ stats, const float* __restrict__ g,
                            const float* __restrict__ be, float inv_n) {
    int f = threadIdx.x;
    if (f < HD) {
        float mu = stats[f] * inv_n;
        float var = stats[64 + f] * inv_n - mu * mu;
        float sc = g[f] * rsqrtf(var + BN_EPS);
        stats[128 + f] = sc;
        stats[192 + f] = be[f] - mu * sc;
    }
}

// ---------------- final FC with fused BN: out = (h*scale+shift) @ fcW + fcb ----------------
__global__ void fc_kernel(const float* __restrict__ h, const float* __restrict__ stats,
                          const float* __restrict__ fcW, const float* __restrict__ fcb,
                          float* __restrict__ out, int n) {
    __shared__ float Ws[HD * DOUT];  // 2 KB
    __shared__ float sc[HD], sh[HD], bb[DOUT];
    int tid = threadIdx.x;
    for (int i = tid; i < HD * DOUT; i += 256) Ws[i] = fcW[i];
    if (tid < HD) { sc[tid] = stats[128 + tid]; sh[tid] = stats[192 + tid]; }
    if (tid < DOUT) bb[tid] = fcb[tid];
    __syncthreads();
    int idx = blockIdx.x * 256 + tid;
    if (idx < n * DOUT) {
        int i = idx >> 3, o = idx & 7;
        const float* hr = h + (size_t)i * HD;
        float acc = bb[o];
#pragma unroll
        for (int k = 0; k < HD; ++k) {
            float v = fmaf(hr[k], sc[k], sh[k]);
            acc = fmaf(v, Ws[k * DOUT + o], acc);
        }
        out[idx] = acc;
    }
}

extern "C" void kernel_launch(void* const* d_in, const int* in_sizes, int n_in,
                              void* d_out, int out_size, void* d_ws, size_t ws_size,
                              hipStream_t stream) {
    const float* x   = (const float*)d_in[0];
    const int*   ei  = (const int*)d_in[1];          // int32 on device per harness
    const float* W1  = (const float*)d_in[2];
    const float* b1  = (const float*)d_in[3];
    const float* g1  = (const float*)d_in[4];
    const float* be1 = (const float*)d_in[5];
    const float* W2  = (const float*)d_in[6];
    const float* b2  = (const float*)d_in[7];
    const float* g2  = (const float*)d_in[8];
    const float* be2 = (const float*)d_in[9];
    const float* W3  = (const float*)d_in[10];
    const float* b3  = (const float*)d_in[11];
    const float* g3  = (const float*)d_in[12];
    const float* be3 = (const float*)d_in[13];
    const float* fcW = (const float*)d_in[14];
    const float* fcb = (const float*)d_in[15];
    float* out = (float*)d_out;

    const int n  = in_sizes[0] / DIN;   // 100000
    const int nE = in_sizes[1] / 2;     // 1000000

    // workspace carve-up (all 256B-aligned), total ~55.7 MB
    char* ws = (char*)d_ws;
    size_t off = 0;
    auto carve = [&](size_t bytes) -> void* {
        void* p = ws + off;
        off = (off + bytes + 255) & ~(size_t)255;
        return p;
    };
    float* dinv  = (float*)carve((size_t)n * 4);          // deg, then in-place rsqrt
    float* en    = (float*)carve((size_t)nE * 4);         // edge_norm
    float* m     = (float*)carve((size_t)n * HD * 4);     // transformed features
    float* h     = (float*)carve((size_t)n * HD * 4);     // agg / hidden
    float* stats = (float*)carve(256 * 4);                // sum[64],sumsq[64],scale[64],shift[64]

    const int total = n * HD;
    const int gElem = (total + 255) / 256;      // elementwise over N*64
    const int gEdge = (nE + 255) / 256;         // thread-per-edge
    const int gRows = (n + 31) / 32;            // 32 rows per block GEMMs
    const float inv_n = 1.0f / (float)n;

    // ---- graph-norm precompute ----
    hipMemsetAsync(dinv, 0, (size_t)n * 4, stream);
    deg_kernel<<<gEdge, 256, 0, stream>>>(ei, dinv, nE);
    dinv_kernel<<<(n + 255) / 256, 256, 0, stream>>>(dinv, n);
    edge_norm_kernel<<<gEdge, 256, 0, stream>>>(ei, dinv, en, nE);

    // ---- layer 1 ----
    gemm_in<<<gRows, 256, 0, stream>>>(x, W1, m, n);
    init_agg<<<gElem, 256, 0, stream>>>(m, dinv, b1, h, total);
    scatter_kernel<<<16384, 256, 0, stream>>>(ei, en, m, h, nE);
    hipMemsetAsync(stats, 0, 128 * 4, stream);
    relu_stats<<<2048, 256, 0, stream>>>(h, stats, total);
    bn_finalize<<<1, 64, 0, stream>>>(stats, g1, be1, inv_n);

    // ---- layer 2 ----
    gemm_hid<<<gRows, 256, 0, stream>>>(h, W2, stats, m, n);
    init_agg<<<gElem, 256, 0, stream>>>(m, dinv, b2, h, total);
    scatter_kernel<<<16384, 256, 0, stream>>>(ei, en, m, h, nE);
    hipMemsetAsync(stats, 0, 128 * 4, stream);
    relu_stats<<<2048, 256, 0, stream>>>(h, stats, total);
    bn_finalize<<<1, 64, 0, stream>>>(stats, g2, be2, inv_n);

    // ---- layer 3 ----
    gemm_hid<<<gRows, 256, 0, stream>>>(h, W3, stats, m, n);
    init_agg<<<gElem, 256, 0, stream>>>(m, dinv, b3, h, total);
    scatter_kernel<<<16384, 256, 0, stream>>>(ei, en, m, h, nE);
    hipMemsetAsync(stats, 0, 128 * 4, stream);
    relu_stats<<<2048, 256, 0, stream>>>(h, stats, total);
    bn_finalize<<<1, 64, 0, stream>>>(stats, g3, be3, inv_n);

    // ---- final FC ----
    fc_kernel<<<(n * DOUT + 255) / 256, 256, 0, stream>>>(h, stats, fcW, fcb, out, n);
}

// Round 3
// 1163.856 us; speedup vs baseline: 1.1348x; 1.1348x over previous
//
#include <hip/hip_runtime.h>

#define HD 64
#define DIN 32
#define DOUT 8
#define BN_EPS 1e-5f

// ---------------- in-degree histogram (int) ----------------
__global__ void hist_kernel(const int* __restrict__ ei, int* __restrict__ cnt, int nE) {
    int e = blockIdx.x * 256 + threadIdx.x;
    if (e < nE) atomicAdd(&cnt[ei[nE + e]], 1);
}

// ---------------- single-block exclusive scan + dinv ----------------
// rowptr[i] = sum_{j<i} cnt[j]; cursor = copy; dinv[i] = rsqrt(cnt[i]+1)
__global__ void scan_kernel(const int* __restrict__ cnt, int* __restrict__ rowptr,
                            int* __restrict__ cursor, float* __restrict__ dinv, int n) {
    __shared__ int part[1024];
    int tid = threadIdx.x;
    int chunk = (n + 1023) >> 10;
    int base = tid * chunk;
    int end = base + chunk; if (end > n) end = n;
    int s = 0;
    for (int j = base; j < end; ++j) s += cnt[j];
    part[tid] = s;
    __syncthreads();
    // Hillis-Steele inclusive scan over 1024 partials
    for (int off = 1; off < 1024; off <<= 1) {
        int v = (tid >= off) ? part[tid - off] : 0;
        __syncthreads();
        part[tid] += v;
        __syncthreads();
    }
    if (tid == 1023) rowptr[n] = part[1023];
    int run = part[tid] - s;   // exclusive prefix for this chunk
    for (int j = base; j < end; ++j) {
        int c = cnt[j];
        rowptr[j] = run;
        cursor[j] = run;
        dinv[j] = rsqrtf((float)c + 1.0f);
        run += c;
    }
}

// ---------------- fill CSR: col[] = src sorted by dst, ens[] = edge norm ----------------
__global__ void fill_kernel(const int* __restrict__ ei, int* __restrict__ cursor,
                            const float* __restrict__ dinv, int* __restrict__ col,
                            float* __restrict__ ens, int nE) {
    int e = blockIdx.x * 256 + threadIdx.x;
    if (e < nE) {
        int s = ei[e];
        int d = ei[nE + e];
        int pos = atomicAdd(&cursor[d], 1);
        col[pos] = s;
        ens[pos] = dinv[s] * dinv[d];
    }
}

// ---------------- GEMM: m = x @ W1  (32 -> 64) ----------------
__global__ void gemm_in(const float* __restrict__ x, const float* __restrict__ W,
                        float* __restrict__ m, int n) {
    __shared__ float Ws[DIN * HD];   // 8 KB
    int tid = threadIdx.x;
    for (int i = tid; i < DIN * HD; i += 256) Ws[i] = W[i];
    __syncthreads();
    int f = tid & 63;
    int w = tid >> 6;
    for (int j = 0; j < 8; ++j) {
        int row = blockIdx.x * 32 + j * 4 + w;
        if (row >= n) return;
        const float* xr = x + (size_t)row * DIN;
        float acc = 0.f;
#pragma unroll
        for (int k = 0; k < DIN; ++k) acc = fmaf(xr[k], Ws[k * HD + f], acc);
        m[(size_t)row * HD + f] = acc;
    }
}

// ---------------- GEMM with BN fused on input: m = (h*sc+sh) @ W (64 -> 64) ----------------
// BN scale/shift computed per-block from raw sums (64 rsqrt, negligible).
__global__ void gemm_hid(const float* __restrict__ h, const float* __restrict__ W,
                         const float* __restrict__ stats, const float* __restrict__ g,
                         const float* __restrict__ be, float* __restrict__ m,
                         int n, float inv_n) {
    __shared__ float Ws[HD * HD];   // 16 KB
    __shared__ float sc[HD], sh[HD];
    int tid = threadIdx.x;
    for (int i = tid; i < HD * HD; i += 256) Ws[i] = W[i];
    if (tid < HD) {
        float mu = stats[tid] * inv_n;
        float var = stats[64 + tid] * inv_n - mu * mu;
        float scv = g[tid] * rsqrtf(var + BN_EPS);
        sc[tid] = scv;
        sh[tid] = be[tid] - mu * scv;
    }
    __syncthreads();
    int f = tid & 63;
    int w = tid >> 6;
    for (int j = 0; j < 8; ++j) {
        int row = blockIdx.x * 32 + j * 4 + w;
        if (row >= n) return;
        const float* hr = h + (size_t)row * HD;
        float acc = 0.f;
#pragma unroll
        for (int k = 0; k < HD; ++k) {
            float v = fmaf(hr[k], sc[k], sh[k]);
            acc = fmaf(v, Ws[k * HD + f], acc);
        }
        m[(size_t)row * HD + f] = acc;
    }
}

// ---------------- fused aggregate: h = relu(sum_in en*m[src] + dinv^2*m[i] + b), + BN stats ----------------
// One wave per dst row; lane = feature. Gather-only, no atomics on h.
__global__ void agg_kernel(const float* __restrict__ m, const int* __restrict__ rowptr,
                           const int* __restrict__ col, const float* __restrict__ ens,
                           const float* __restrict__ dinv, const float* __restrict__ b,
                           float* __restrict__ h, float* __restrict__ stats, int n) {
    int tid = threadIdx.x;
    int lane = tid & 63;
    int wid = (blockIdx.x * blockDim.x + tid) >> 6;
    int nw = (gridDim.x * blockDim.x) >> 6;
    float bf = b[lane];
    float s = 0.f, s2 = 0.f;
    for (int i = wid; i < n; i += nw) {
        int p0 = rowptr[i], p1 = rowptr[i + 1];
        float di = dinv[i];
        float acc = fmaf(di * di, m[(size_t)i * HD + lane], bf);
        if (p0 < p1) {
            int sidx = col[p0];
            float wgt = ens[p0];
            for (int p = p0 + 1; p < p1; ++p) {
                int sidx2 = col[p];       // prefetch next edge's index/weight
                float wgt2 = ens[p];
                acc = fmaf(wgt, m[(size_t)sidx * HD + lane], acc);
                sidx = sidx2; wgt = wgt2;
            }
            acc = fmaf(wgt, m[(size_t)sidx * HD + lane], acc);
        }
        float v = fmaxf(acc, 0.f);
        h[(size_t)i * HD + lane] = v;
        s += v;
        s2 += v * v;
    }
    __shared__ float ls[256], ls2[256];
    ls[tid] = s; ls2[tid] = s2;
    __syncthreads();
    if (tid < 64) {
        s = ls[tid] + ls[tid + 64] + ls[tid + 128] + ls[tid + 192];
        s2 = ls2[tid] + ls2[tid + 64] + ls2[tid + 128] + ls2[tid + 192];
        atomicAdd(&stats[tid], s);
        atomicAdd(&stats[64 + tid], s2);
    }
}

// ---------------- final FC with fused BN: out = (h*sc+sh) @ fcW + fcb ----------------
__global__ void fc_kernel(const float* __restrict__ h, const float* __restrict__ stats,
                          const float* __restrict__ g, const float* __restrict__ be,
                          const float* __restrict__ fcW, const float* __restrict__ fcb,
                          float* __restrict__ out, int n, float inv_n) {
    __shared__ float Ws[HD * DOUT];  // 2 KB
    __shared__ float sc[HD], sh[HD], bb[DOUT];
    int tid = threadIdx.x;
    for (int i = tid; i < HD * DOUT; i += 256) Ws[i] = fcW[i];
    if (tid < HD) {
        float mu = stats[tid] * inv_n;
        float var = stats[64 + tid] * inv_n - mu * mu;
        float scv = g[tid] * rsqrtf(var + BN_EPS);
        sc[tid] = scv;
        sh[tid] = be[tid] - mu * scv;
    }
    if (tid < DOUT) bb[tid] = fcb[tid];
    __syncthreads();
    int idx = blockIdx.x * 256 + tid;
    if (idx < n * DOUT) {
        int i = idx >> 3, o = idx & 7;
        const float* hr = h + (size_t)i * HD;
        float acc = bb[o];
#pragma unroll
        for (int k = 0; k < HD; ++k) {
            float v = fmaf(hr[k], sc[k], sh[k]);
            acc = fmaf(v, Ws[k * DOUT + o], acc);
        }
        out[idx] = acc;
    }
}

extern "C" void kernel_launch(void* const* d_in, const int* in_sizes, int n_in,
                              void* d_out, int out_size, void* d_ws, size_t ws_size,
                              hipStream_t stream) {
    const float* x   = (const float*)d_in[0];
    const int*   ei  = (const int*)d_in[1];          // int32 on device per harness
    const float* W1  = (const float*)d_in[2];
    const float* b1  = (const float*)d_in[3];
    const float* g1  = (const float*)d_in[4];
    const float* be1 = (const float*)d_in[5];
    const float* W2  = (const float*)d_in[6];
    const float* b2  = (const float*)d_in[7];
    const float* g2  = (const float*)d_in[8];
    const float* be2 = (const float*)d_in[9];
    const float* W3  = (const float*)d_in[10];
    const float* b3  = (const float*)d_in[11];
    const float* g3  = (const float*)d_in[12];
    const float* be3 = (const float*)d_in[13];
    const float* fcW = (const float*)d_in[14];
    const float* fcb = (const float*)d_in[15];
    float* out = (float*)d_out;

    const int n  = in_sizes[0] / DIN;   // 100000
    const int nE = in_sizes[1] / 2;     // 1000000

    // workspace carve-up (256B-aligned)
    char* ws = (char*)d_ws;
    size_t off = 0;
    auto carve = [&](size_t bytes) -> void* {
        void* p = ws + off;
        off = (off + bytes + 255) & ~(size_t)255;
        return p;
    };
    int*   cnt    = (int*)carve((size_t)n * 4);           // in-degree histogram
    int*   rowptr = (int*)carve((size_t)(n + 1) * 4);     // CSR row pointers
    int*   cursor = (int*)carve((size_t)n * 4);           // fill cursors
    float* dinv   = (float*)carve((size_t)n * 4);
    int*   col    = (int*)carve((size_t)nE * 4);          // src sorted by dst
    float* ens    = (float*)carve((size_t)nE * 4);        // edge norm sorted by dst
    float* m      = (float*)carve((size_t)n * HD * 4);    // transformed features
    float* h      = (float*)carve((size_t)n * HD * 4);    // hidden
    float* stats  = (float*)carve(3 * 128 * 4);           // per-layer sum[64]+sumsq[64]

    const int gEdge = (nE + 255) / 256;
    const int gRows = (n + 31) / 32;
    const float inv_n = 1.0f / (float)n;

    // ---- CSR + norm precompute ----
    hipMemsetAsync(cnt, 0, (size_t)n * 4, stream);
    hipMemsetAsync(stats, 0, 3 * 128 * 4, stream);
    hist_kernel<<<gEdge, 256, 0, stream>>>(ei, cnt, nE);
    scan_kernel<<<1, 1024, 0, stream>>>(cnt, rowptr, cursor, dinv, n);
    fill_kernel<<<gEdge, 256, 0, stream>>>(ei, cursor, dinv, col, ens, nE);

    // ---- layer 1 ----
    gemm_in<<<gRows, 256, 0, stream>>>(x, W1, m, n);
    agg_kernel<<<2048, 256, 0, stream>>>(m, rowptr, col, ens, dinv, b1, h, stats, n);

    // ---- layer 2 ----
    gemm_hid<<<gRows, 256, 0, stream>>>(h, W2, stats, g1, be1, m, n, inv_n);
    agg_kernel<<<2048, 256, 0, stream>>>(m, rowptr, col, ens, dinv, b2, h, stats + 128, n);

    // ---- layer 3 ----
    gemm_hid<<<gRows, 256, 0, stream>>>(h, W3, stats + 128, g2, be2, m, n, inv_n);
    agg_kernel<<<2048, 256, 0, stream>>>(m, rowptr, col, ens, dinv, b3, h, stats + 256, n);

    // ---- final FC (BN3 fused) ----
    fc_kernel<<<(n * DOUT + 255) / 256, 256, 0, stream>>>(h, stats + 256, g3, be3, fcW, fcb, out, n, inv_n);
}

// Round 4
// 879.479 us; speedup vs baseline: 1.5017x; 1.3233x over previous
//
#include <hip/hip_runtime.h>

#define HD 64
#define DIN 32
#define DOUT 8
#define BN_EPS 1e-5f

// ---------------- in-degree histogram (int) ----------------
__global__ void hist_kernel(const int* __restrict__ ei, int* __restrict__ cnt, int nE) {
    int e = blockIdx.x * 256 + threadIdx.x;
    if (e < nE) atomicAdd(&cnt[ei[nE + e]], 1);
}

// ---------------- 3-phase parallel exclusive scan ----------------
// phase 1: per-block (256 elems) sums
__global__ void scan_partial(const int* __restrict__ cnt, int* __restrict__ part, int n) {
    __shared__ int s[256];
    int tid = threadIdx.x;
    int i = blockIdx.x * 256 + tid;
    s[tid] = (i < n) ? cnt[i] : 0;
    __syncthreads();
#pragma unroll
    for (int off = 128; off > 0; off >>= 1) {
        if (tid < off) s[tid] += s[tid + off];
        __syncthreads();
    }
    if (tid == 0) part[blockIdx.x] = s[0];
}

// phase 2: single-block exclusive scan of nb (<=1024) partials, in place
__global__ void scan_block(int* __restrict__ part, int nb, int* __restrict__ rowptr,
                           int n, int nE) {
    __shared__ int s[1024];
    int tid = threadIdx.x;
    int v = (tid < nb) ? part[tid] : 0;
    s[tid] = v;
    __syncthreads();
    for (int off = 1; off < 1024; off <<= 1) {
        int t = (tid >= off) ? s[tid - off] : 0;
        __syncthreads();
        s[tid] += t;
        __syncthreads();
    }
    if (tid < nb) part[tid] = s[tid] - v;   // exclusive
    if (tid == 0) rowptr[n] = nE;           // total is nE by construction
}

// phase 3: per-block exclusive scan + block offset -> rowptr/cursor/dinv
__global__ void scan_final(const int* __restrict__ cnt, const int* __restrict__ part,
                           int* __restrict__ rowptr, int* __restrict__ cursor,
                           float* __restrict__ dinv, int n) {
    __shared__ int s[256];
    int tid = threadIdx.x;
    int i = blockIdx.x * 256 + tid;
    int c = (i < n) ? cnt[i] : 0;
    s[tid] = c;
    __syncthreads();
    for (int off = 1; off < 256; off <<= 1) {
        int t = (tid >= off) ? s[tid - off] : 0;
        __syncthreads();
        s[tid] += t;
        __syncthreads();
    }
    if (i < n) {
        int ex = s[tid] - c + part[blockIdx.x];
        rowptr[i] = ex;
        cursor[i] = ex;
        dinv[i] = rsqrtf((float)c + 1.0f);
    }
}

// ---------------- fill CSR: col[] = src sorted by dst, ens[] = edge norm ----------------
__global__ void fill_kernel(const int* __restrict__ ei, int* __restrict__ cursor,
                            const float* __restrict__ dinv, int* __restrict__ col,
                            float* __restrict__ ens, int nE) {
    int e = blockIdx.x * 256 + threadIdx.x;
    if (e < nE) {
        int s = ei[e];
        int d = ei[nE + e];
        int pos = atomicAdd(&cursor[d], 1);
        col[pos] = s;
        ens[pos] = dinv[s] * dinv[d];
    }
}

// ---------------- GEMM: m = x @ W1  (32 -> 64) ----------------
__global__ void gemm_in(const float* __restrict__ x, const float* __restrict__ W,
                        float* __restrict__ m, int n) {
    __shared__ float Ws[DIN * HD];   // 8 KB
    int tid = threadIdx.x;
    for (int i = tid; i < DIN * HD; i += 256) Ws[i] = W[i];
    __syncthreads();
    int f = tid & 63;
    int w = tid >> 6;
    for (int j = 0; j < 8; ++j) {
        int row = blockIdx.x * 32 + j * 4 + w;
        if (row >= n) return;
        const float* xr = x + (size_t)row * DIN;
        float acc = 0.f;
#pragma unroll
        for (int k = 0; k < DIN; ++k) acc = fmaf(xr[k], Ws[k * HD + f], acc);
        m[(size_t)row * HD + f] = acc;
    }
}

// ---------------- GEMM with BN fused on input: m = (h*sc+sh) @ W (64 -> 64) ----------------
__global__ void gemm_hid(const float* __restrict__ h, const float* __restrict__ W,
                         const float* __restrict__ stats, const float* __restrict__ g,
                         const float* __restrict__ be, float* __restrict__ m,
                         int n, float inv_n) {
    __shared__ float Ws[HD * HD];   // 16 KB
    __shared__ float sc[HD], sh[HD];
    int tid = threadIdx.x;
    for (int i = tid; i < HD * HD; i += 256) Ws[i] = W[i];
    if (tid < HD) {
        float mu = stats[tid] * inv_n;
        float var = stats[64 + tid] * inv_n - mu * mu;
        float scv = g[tid] * rsqrtf(var + BN_EPS);
        sc[tid] = scv;
        sh[tid] = be[tid] - mu * scv;
    }
    __syncthreads();
    int f = tid & 63;
    int w = tid >> 6;
    for (int j = 0; j < 8; ++j) {
        int row = blockIdx.x * 32 + j * 4 + w;
        if (row >= n) return;
        const float* hr = h + (size_t)row * HD;
        float acc = 0.f;
#pragma unroll
        for (int k = 0; k < HD; ++k) {
            float v = fmaf(hr[k], sc[k], sh[k]);
            acc = fmaf(v, Ws[k * HD + f], acc);
        }
        m[(size_t)row * HD + f] = acc;
    }
}

// ---------------- fused aggregate: h = relu(sum_in en*m[src] + dinv^2*m[i] + b), + BN stats ----------------
__global__ void agg_kernel(const float* __restrict__ m, const int* __restrict__ rowptr,
                           const int* __restrict__ col, const float* __restrict__ ens,
                           const float* __restrict__ dinv, const float* __restrict__ b,
                           float* __restrict__ h, float* __restrict__ stats, int n) {
    int tid = threadIdx.x;
    int lane = tid & 63;
    int wid = (blockIdx.x * blockDim.x + tid) >> 6;
    int nw = (gridDim.x * blockDim.x) >> 6;
    float bf = b[lane];
    float s = 0.f, s2 = 0.f;
    for (int i = wid; i < n; i += nw) {
        int p0 = rowptr[i], p1 = rowptr[i + 1];
        float di = dinv[i];
        float acc = fmaf(di * di, m[(size_t)i * HD + lane], bf);
        if (p0 < p1) {
            int sidx = col[p0];
            float wgt = ens[p0];
            for (int p = p0 + 1; p < p1; ++p) {
                int sidx2 = col[p];       // software prefetch next edge
                float wgt2 = ens[p];
                acc = fmaf(wgt, m[(size_t)sidx * HD + lane], acc);
                sidx = sidx2; wgt = wgt2;
            }
            acc = fmaf(wgt, m[(size_t)sidx * HD + lane], acc);
        }
        float v = fmaxf(acc, 0.f);
        h[(size_t)i * HD + lane] = v;
        s += v;
        s2 += v * v;
    }
    __shared__ float ls[256], ls2[256];
    ls[tid] = s; ls2[tid] = s2;
    __syncthreads();
    if (tid < 64) {
        s = ls[tid] + ls[tid + 64] + ls[tid + 128] + ls[tid + 192];
        s2 = ls2[tid] + ls2[tid + 64] + ls2[tid + 128] + ls2[tid + 192];
        atomicAdd(&stats[tid], s);
        atomicAdd(&stats[64 + tid], s2);
    }
}

// ---------------- final FC with fused BN: out = (h*sc+sh) @ fcW + fcb ----------------
__global__ void fc_kernel(const float* __restrict__ h, const float* __restrict__ stats,
                          const float* __restrict__ g, const float* __restrict__ be,
                          const float* __restrict__ fcW, const float* __restrict__ fcb,
                          float* __restrict__ out, int n, float inv_n) {
    __shared__ float Ws[HD * DOUT];  // 2 KB
    __shared__ float sc[HD], sh[HD], bb[DOUT];
    int tid = threadIdx.x;
    for (int i = tid; i < HD * DOUT; i += 256) Ws[i] = fcW[i];
    if (tid < HD) {
        float mu = stats[tid] * inv_n;
        float var = stats[64 + tid] * inv_n - mu * mu;
        float scv = g[tid] * rsqrtf(var + BN_EPS);
        sc[tid] = scv;
        sh[tid] = be[tid] - mu * scv;
    }
    if (tid < DOUT) bb[tid] = fcb[tid];
    __syncthreads();
    int idx = blockIdx.x * 256 + tid;
    if (idx < n * DOUT) {
        int i = idx >> 3, o = idx & 7;
        const float* hr = h + (size_t)i * HD;
        float acc = bb[o];
#pragma unroll
        for (int k = 0; k < HD; ++k) {
            float v = fmaf(hr[k], sc[k], sh[k]);
            acc = fmaf(v, Ws[k * DOUT + o], acc);
        }
        out[idx] = acc;
    }
}

extern "C" void kernel_launch(void* const* d_in, const int* in_sizes, int n_in,
                              void* d_out, int out_size, void* d_ws, size_t ws_size,
                              hipStream_t stream) {
    const float* x   = (const float*)d_in[0];
    const int*   ei  = (const int*)d_in[1];          // int32 on device per harness
    const float* W1  = (const float*)d_in[2];
    const float* b1  = (const float*)d_in[3];
    const float* g1  = (const float*)d_in[4];
    const float* be1 = (const float*)d_in[5];
    const float* W2  = (const float*)d_in[6];
    const float* b2  = (const float*)d_in[7];
    const float* g2  = (const float*)d_in[8];
    const float* be2 = (const float*)d_in[9];
    const float* W3  = (const float*)d_in[10];
    const float* b3  = (const float*)d_in[11];
    const float* g3  = (const float*)d_in[12];
    const float* be3 = (const float*)d_in[13];
    const float* fcW = (const float*)d_in[14];
    const float* fcb = (const float*)d_in[15];
    float* out = (float*)d_out;

    const int n  = in_sizes[0] / DIN;   // 100000
    const int nE = in_sizes[1] / 2;     // 1000000

    // workspace carve-up (256B-aligned)
    char* ws = (char*)d_ws;
    size_t off = 0;
    auto carve = [&](size_t bytes) -> void* {
        void* p = ws + off;
        off = (off + bytes + 255) & ~(size_t)255;
        return p;
    };
    int*   cnt    = (int*)carve((size_t)n * 4);           // in-degree histogram
    int*   rowptr = (int*)carve((size_t)(n + 1) * 4);     // CSR row pointers
    int*   cursor = (int*)carve((size_t)n * 4);           // fill cursors
    float* dinv   = (float*)carve((size_t)n * 4);
    int*   part   = (int*)carve(1024 * 4);                // scan partials
    int*   col    = (int*)carve((size_t)nE * 4);          // src sorted by dst
    float* ens    = (float*)carve((size_t)nE * 4);        // edge norm sorted by dst
    float* m      = (float*)carve((size_t)n * HD * 4);    // transformed features
    float* h      = (float*)carve((size_t)n * HD * 4);    // hidden
    float* stats  = (float*)carve(3 * 128 * 4);           // per-layer sum[64]+sumsq[64]

    const int gEdge = (nE + 255) / 256;
    const int gRows = (n + 31) / 32;
    const int nb    = (n + 255) / 256;      // scan blocks (391 <= 1024)
    const float inv_n = 1.0f / (float)n;

    // ---- CSR + norm precompute ----
    hipMemsetAsync(cnt, 0, (size_t)n * 4, stream);
    hipMemsetAsync(stats, 0, 3 * 128 * 4, stream);
    hist_kernel<<<gEdge, 256, 0, stream>>>(ei, cnt, nE);
    scan_partial<<<nb, 256, 0, stream>>>(cnt, part, n);
    scan_block<<<1, 1024, 0, stream>>>(part, nb, rowptr, n, nE);
    scan_final<<<nb, 256, 0, stream>>>(cnt, part, rowptr, cursor, dinv, n);
    fill_kernel<<<gEdge, 256, 0, stream>>>(ei, cursor, dinv, col, ens, nE);

    // ---- layer 1 ----
    gemm_in<<<gRows, 256, 0, stream>>>(x, W1, m, n);
    agg_kernel<<<2048, 256, 0, stream>>>(m, rowptr, col, ens, dinv, b1, h, stats, n);

    // ---- layer 2 ----
    gemm_hid<<<gRows, 256, 0, stream>>>(h, W2, stats, g1, be1, m, n, inv_n);
    agg_kernel<<<2048, 256, 0, stream>>>(m, rowptr, col, ens, dinv, b2, h, stats + 128, n);

    // ---- layer 3 ----
    gemm_hid<<<gRows, 256, 0, stream>>>(h, W3, stats + 128, g2, be2, m, n, inv_n);
    agg_kernel<<<2048, 256, 0, stream>>>(m, rowptr, col, ens, dinv, b3, h, stats + 256, n);

    // ---- final FC (BN3 fused) ----
    fc_kernel<<<(n * DOUT + 255) / 256, 256, 0, stream>>>(h, stats + 256, g3, be3, fcW, fcb, out, n, inv_n);
}

// Round 5
// 750.929 us; speedup vs baseline: 1.7588x; 1.1712x over previous
//
#include <hip/hip_runtime.h>

#define HD 64
#define DIN 32
#define DOUT 8
#define BN_EPS 1e-5f

// ---------------- in-degree histogram (int) ----------------
__global__ void hist_kernel(const int* __restrict__ ei, int* __restrict__ cnt, int nE) {
    int e = blockIdx.x * 256 + threadIdx.x;
    if (e < nE) atomicAdd(&cnt[ei[nE + e]], 1);
}

// ---------------- 3-phase parallel exclusive scan ----------------
__global__ void scan_partial(const int* __restrict__ cnt, int* __restrict__ part, int n) {
    __shared__ int s[256];
    int tid = threadIdx.x;
    int i = blockIdx.x * 256 + tid;
    s[tid] = (i < n) ? cnt[i] : 0;
    __syncthreads();
#pragma unroll
    for (int off = 128; off > 0; off >>= 1) {
        if (tid < off) s[tid] += s[tid + off];
        __syncthreads();
    }
    if (tid == 0) part[blockIdx.x] = s[0];
}

__global__ void scan_block(int* __restrict__ part, int nb, int* __restrict__ rowptr,
                           int n, int nE) {
    __shared__ int s[1024];
    int tid = threadIdx.x;
    int v = (tid < nb) ? part[tid] : 0;
    s[tid] = v;
    __syncthreads();
    for (int off = 1; off < 1024; off <<= 1) {
        int t = (tid >= off) ? s[tid - off] : 0;
        __syncthreads();
        s[tid] += t;
        __syncthreads();
    }
    if (tid < nb) part[tid] = s[tid] - v;   // exclusive
    if (tid == 0) rowptr[n] = nE;
}

__global__ void scan_final(const int* __restrict__ cnt, const int* __restrict__ part,
                           int* __restrict__ rowptr, int* __restrict__ cursor,
                           float* __restrict__ dinv, int n) {
    __shared__ int s[256];
    int tid = threadIdx.x;
    int i = blockIdx.x * 256 + tid;
    int c = (i < n) ? cnt[i] : 0;
    s[tid] = c;
    __syncthreads();
    for (int off = 1; off < 256; off <<= 1) {
        int t = (tid >= off) ? s[tid - off] : 0;
        __syncthreads();
        s[tid] += t;
        __syncthreads();
    }
    if (i < n) {
        int ex = s[tid] - c + part[blockIdx.x];
        rowptr[i] = ex;
        cursor[i] = ex;
        dinv[i] = rsqrtf((float)c + 1.0f);
    }
}

// ---------------- fill CSR ----------------
__global__ void fill_kernel(const int* __restrict__ ei, int* __restrict__ cursor,
                            const float* __restrict__ dinv, int* __restrict__ col,
                            float* __restrict__ ens, int nE) {
    int e = blockIdx.x * 256 + threadIdx.x;
    if (e < nE) {
        int s = ei[e];
        int d = ei[nE + e];
        int pos = atomicAdd(&cursor[d], 1);
        col[pos] = s;
        ens[pos] = dinv[s] * dinv[d];
    }
}

// ---------------- GEMM: m = x @ W1 (32->64), LDS-tiled, coalesced float4 ----------------
__global__ void gemm_in(const float* __restrict__ x, const float* __restrict__ W,
                        float* __restrict__ m, int n) {
    __shared__ float Ws[DIN * HD];   // 8 KB, [k][f]
    __shared__ float hs[64 * DIN];   // 8 KB, [r][k]
    int tid = threadIdx.x;
    const float4* W4 = (const float4*)W;
    float4* Ws4 = (float4*)Ws;
#pragma unroll
    for (int i = 0; i < 2; ++i) Ws4[tid + 256 * i] = W4[tid + 256 * i];
    int base = blockIdx.x * 64;
    const float4* x4 = (const float4*)(x + (size_t)base * DIN);
    float4* hs4 = (float4*)hs;
#pragma unroll
    for (int i = 0; i < 2; ++i) {
        int q = tid + 256 * i;           // float4 index; 8 per row
        int r = q >> 3;
        hs4[q] = (base + r < n) ? x4[q] : make_float4(0.f, 0.f, 0.f, 0.f);
    }
    __syncthreads();
    int f = tid & 63, w = tid >> 6;
    for (int r = w * 16; r < w * 16 + 16; ++r) {
        int row = base + r;
        if (row >= n) break;
        const float4* hr4 = (const float4*)&hs[r * DIN];
        float acc = 0.f;
#pragma unroll
        for (int kk = 0; kk < 8; ++kk) {
            float4 hv = hr4[kk];
            acc = fmaf(hv.x, Ws[(kk * 4 + 0) * HD + f], acc);
            acc = fmaf(hv.y, Ws[(kk * 4 + 1) * HD + f], acc);
            acc = fmaf(hv.z, Ws[(kk * 4 + 2) * HD + f], acc);
            acc = fmaf(hv.w, Ws[(kk * 4 + 3) * HD + f], acc);
        }
        m[(size_t)row * HD + f] = acc;
    }
}

// ---------------- GEMM + fused BN input: m = (h*sc+sh) @ W (64->64), LDS-tiled ----------------
__global__ void gemm_hid(const float* __restrict__ h, const float* __restrict__ W,
                         const float* __restrict__ stats, const float* __restrict__ g,
                         const float* __restrict__ be, float* __restrict__ m,
                         int n, float inv_n) {
    __shared__ float Ws[HD * HD];    // 16 KB, [k][f]
    __shared__ float hs[64 * HD];    // 16 KB, [r][k], BN pre-applied
    __shared__ float sc[HD], sh[HD];
    int tid = threadIdx.x;
    if (tid < HD) {
        float mu = stats[tid] * inv_n;
        float var = stats[64 + tid] * inv_n - mu * mu;
        float scv = g[tid] * rsqrtf(var + BN_EPS);
        sc[tid] = scv;
        sh[tid] = be[tid] - mu * scv;
    }
    const float4* W4 = (const float4*)W;
    float4* Ws4 = (float4*)Ws;
#pragma unroll
    for (int i = 0; i < 4; ++i) Ws4[tid + 256 * i] = W4[tid + 256 * i];
    __syncthreads();   // sc/sh ready before tile BN
    int base = blockIdx.x * 64;
    const float4* h4 = (const float4*)(h + (size_t)base * HD);
    float4* hs4 = (float4*)hs;
#pragma unroll
    for (int i = 0; i < 4; ++i) {
        int q = tid + 256 * i;           // float4 index; 16 per row
        int r = q >> 4;
        int c = (q & 15) * 4;
        float4 v = make_float4(0.f, 0.f, 0.f, 0.f);
        if (base + r < n) {
            v = h4[q];
            v.x = fmaf(v.x, sc[c + 0], sh[c + 0]);
            v.y = fmaf(v.y, sc[c + 1], sh[c + 1]);
            v.z = fmaf(v.z, sc[c + 2], sh[c + 2]);
            v.w = fmaf(v.w, sc[c + 3], sh[c + 3]);
        }
        hs4[q] = v;
    }
    __syncthreads();
    int f = tid & 63, w = tid >> 6;
    for (int r = w * 16; r < w * 16 + 16; ++r) {
        int row = base + r;
        if (row >= n) break;
        const float4* hr4 = (const float4*)&hs[r * HD];
        float acc = 0.f;
#pragma unroll
        for (int kk = 0; kk < 16; ++kk) {
            float4 hv = hr4[kk];
            acc = fmaf(hv.x, Ws[(kk * 4 + 0) * HD + f], acc);
            acc = fmaf(hv.y, Ws[(kk * 4 + 1) * HD + f], acc);
            acc = fmaf(hv.z, Ws[(kk * 4 + 2) * HD + f], acc);
            acc = fmaf(hv.w, Ws[(kk * 4 + 3) * HD + f], acc);
        }
        m[(size_t)row * HD + f] = acc;
    }
}

// ---------------- fused aggregate (gather, no atomics) + ReLU + BN stats ----------------
__global__ void agg_kernel(const float* __restrict__ m, const int* __restrict__ rowptr,
                           const int* __restrict__ col, const float* __restrict__ ens,
                           const float* __restrict__ dinv, const float* __restrict__ b,
                           float* __restrict__ h, float* __restrict__ stats, int n) {
    int tid = threadIdx.x;
    int lane = tid & 63;
    int wid = (blockIdx.x * blockDim.x + tid) >> 6;
    int nw = (gridDim.x * blockDim.x) >> 6;
    float bf = b[lane];
    float s = 0.f, s2 = 0.f;
    for (int i = wid; i < n; i += nw) {
        int p0 = rowptr[i], p1 = rowptr[i + 1];
        float di = dinv[i];
        float acc = fmaf(di * di, m[(size_t)i * HD + lane], bf);
        if (p0 < p1) {
            int sidx = col[p0];
            float wgt = ens[p0];
            for (int p = p0 + 1; p < p1; ++p) {
                int sidx2 = col[p];
                float wgt2 = ens[p];
                acc = fmaf(wgt, m[(size_t)sidx * HD + lane], acc);
                sidx = sidx2; wgt = wgt2;
            }
            acc = fmaf(wgt, m[(size_t)sidx * HD + lane], acc);
        }
        float v = fmaxf(acc, 0.f);
        h[(size_t)i * HD + lane] = v;
        s += v;
        s2 += v * v;
    }
    __shared__ float ls[256], ls2[256];
    ls[tid] = s; ls2[tid] = s2;
    __syncthreads();
    if (tid < 64) {
        s = ls[tid] + ls[tid + 64] + ls[tid + 128] + ls[tid + 192];
        s2 = ls2[tid] + ls2[tid + 64] + ls2[tid + 128] + ls2[tid + 192];
        atomicAdd(&stats[tid], s);
        atomicAdd(&stats[64 + tid], s2);
    }
}

// ---------------- final FC + fused BN, LDS-tiled ----------------
__global__ void fc_kernel(const float* __restrict__ h, const float* __restrict__ stats,
                          const float* __restrict__ g, const float* __restrict__ be,
                          const float* __restrict__ fcW, const float* __restrict__ fcb,
                          float* __restrict__ out, int n, float inv_n) {
    __shared__ float Ws[HD * DOUT];  // 2 KB, [k][o]
    __shared__ float hs[32 * 68];    // 8.5 KB, padded stride 68
    __shared__ float sc[HD], sh[HD], bb[DOUT];
    int tid = threadIdx.x;
    if (tid < 128) ((float4*)Ws)[tid] = ((const float4*)fcW)[tid];
    if (tid < HD) {
        float mu = stats[tid] * inv_n;
        float var = stats[64 + tid] * inv_n - mu * mu;
        float scv = g[tid] * rsqrtf(var + BN_EPS);
        sc[tid] = scv;
        sh[tid] = be[tid] - mu * scv;
    }
    if (tid < DOUT) bb[tid] = fcb[tid];
    __syncthreads();
    int base = blockIdx.x * 32;
    const float4* h4 = (const float4*)(h + (size_t)base * HD);
#pragma unroll
    for (int i = 0; i < 2; ++i) {
        int q = tid + 256 * i;           // 512 float4 total; 16 per row
        int r = q >> 4;
        int c = (q & 15) * 4;
        float4 v = make_float4(0.f, 0.f, 0.f, 0.f);
        if (base + r < n) {
            v = h4[q];
            v.x = fmaf(v.x, sc[c + 0], sh[c + 0]);
            v.y = fmaf(v.y, sc[c + 1], sh[c + 1]);
            v.z = fmaf(v.z, sc[c + 2], sh[c + 2]);
            v.w = fmaf(v.w, sc[c + 3], sh[c + 3]);
        }
        *(float4*)&hs[r * 68 + c] = v;   // 68-float stride: 272 B = 16B-aligned
    }
    __syncthreads();
    int r = tid >> 3, o = tid & 7;
    const float4* hr4 = (const float4*)&hs[r * 68];
    float acc = bb[o];
#pragma unroll
    for (int kk = 0; kk < 16; ++kk) {
        float4 hv = hr4[kk];
        acc = fmaf(hv.x, Ws[(kk * 4 + 0) * DOUT + o], acc);
        acc = fmaf(hv.y, Ws[(kk * 4 + 1) * DOUT + o], acc);
        acc = fmaf(hv.z, Ws[(kk * 4 + 2) * DOUT + o], acc);
        acc = fmaf(hv.w, Ws[(kk * 4 + 3) * DOUT + o], acc);
    }
    if (base + r < n) out[(size_t)(base + r) * DOUT + o] = acc;
}

extern "C" void kernel_launch(void* const* d_in, const int* in_sizes, int n_in,
                              void* d_out, int out_size, void* d_ws, size_t ws_size,
                              hipStream_t stream) {
    const float* x   = (const float*)d_in[0];
    const int*   ei  = (const int*)d_in[1];
    const float* W1  = (const float*)d_in[2];
    const float* b1  = (const float*)d_in[3];
    const float* g1  = (const float*)d_in[4];
    const float* be1 = (const float*)d_in[5];
    const float* W2  = (const float*)d_in[6];
    const float* b2  = (const float*)d_in[7];
    const float* g2  = (const float*)d_in[8];
    const float* be2 = (const float*)d_in[9];
    const float* W3  = (const float*)d_in[10];
    const float* b3  = (const float*)d_in[11];
    const float* g3  = (const float*)d_in[12];
    const float* be3 = (const float*)d_in[13];
    const float* fcW = (const float*)d_in[14];
    const float* fcb = (const float*)d_in[15];
    float* out = (float*)d_out;

    const int n  = in_sizes[0] / DIN;   // 100000
    const int nE = in_sizes[1] / 2;     // 1000000

    char* ws = (char*)d_ws;
    size_t off = 0;
    auto carve = [&](size_t bytes) -> void* {
        void* p = ws + off;
        off = (off + bytes + 255) & ~(size_t)255;
        return p;
    };
    int*   cnt    = (int*)carve((size_t)n * 4);
    int*   rowptr = (int*)carve((size_t)(n + 1) * 4);
    int*   cursor = (int*)carve((size_t)n * 4);
    float* dinv   = (float*)carve((size_t)n * 4);
    int*   part   = (int*)carve(1024 * 4);
    int*   col    = (int*)carve((size_t)nE * 4);
    float* ens    = (float*)carve((size_t)nE * 4);
    float* m      = (float*)carve((size_t)n * HD * 4);
    float* h      = (float*)carve((size_t)n * HD * 4);
    float* stats  = (float*)carve(3 * 128 * 4);

    const int gEdge = (nE + 255) / 256;
    const int g64   = (n + 63) / 64;
    const int g32   = (n + 31) / 32;
    const int nb    = (n + 255) / 256;
    const float inv_n = 1.0f / (float)n;

    // ---- CSR + norm precompute ----
    hipMemsetAsync(cnt, 0, (size_t)n * 4, stream);
    hipMemsetAsync(stats, 0, 3 * 128 * 4, stream);
    hist_kernel<<<gEdge, 256, 0, stream>>>(ei, cnt, nE);
    scan_partial<<<nb, 256, 0, stream>>>(cnt, part, n);
    scan_block<<<1, 1024, 0, stream>>>(part, nb, rowptr, n, nE);
    scan_final<<<nb, 256, 0, stream>>>(cnt, part, rowptr, cursor, dinv, n);
    fill_kernel<<<gEdge, 256, 0, stream>>>(ei, cursor, dinv, col, ens, nE);

    // ---- layer 1 ----
    gemm_in<<<g64, 256, 0, stream>>>(x, W1, m, n);
    agg_kernel<<<2048, 256, 0, stream>>>(m, rowptr, col, ens, dinv, b1, h, stats, n);

    // ---- layer 2 ----
    gemm_hid<<<g64, 256, 0, stream>>>(h, W2, stats, g1, be1, m, n, inv_n);
    agg_kernel<<<2048, 256, 0, stream>>>(m, rowptr, col, ens, dinv, b2, h, stats + 128, n);

    // ---- layer 3 ----
    gemm_hid<<<g64, 256, 0, stream>>>(h, W3, stats + 128, g2, be2, m, n, inv_n);
    agg_kernel<<<2048, 256, 0, stream>>>(m, rowptr, col, ens, dinv, b3, h, stats + 256, n);

    // ---- final FC ----
    fc_kernel<<<g32, 256, 0, stream>>>(h, stats + 256, g3, be3, fcW, fcb, out, n, inv_n);
}

// Round 6
// 666.311 us; speedup vs baseline: 1.9821x; 1.1270x over previous
//
#include <hip/hip_runtime.h>

#define HD 64
#define DIN 32
#define DOUT 8
#define BN_EPS 1e-5f

typedef unsigned short u16;
typedef unsigned int u32;

__device__ __forceinline__ float b2f(u16 v) {
    return __uint_as_float(((u32)v) << 16);
}
__device__ __forceinline__ u16 f2b(float f) {
    u32 u = __float_as_uint(f);
    return (u16)((u + 0x7fffu + ((u >> 16) & 1u)) >> 16);   // RNE
}

// ---------------- in-degree histogram (int) ----------------
__global__ void hist_kernel(const int* __restrict__ ei, int* __restrict__ cnt, int nE) {
    int e = blockIdx.x * 256 + threadIdx.x;
    if (e < nE) atomicAdd(&cnt[ei[nE + e]], 1);
}

// ---------------- 3-phase parallel exclusive scan ----------------
__global__ void scan_partial(const int* __restrict__ cnt, int* __restrict__ part, int n) {
    __shared__ int s[256];
    int tid = threadIdx.x;
    int i = blockIdx.x * 256 + tid;
    s[tid] = (i < n) ? cnt[i] : 0;
    __syncthreads();
#pragma unroll
    for (int off = 128; off > 0; off >>= 1) {
        if (tid < off) s[tid] += s[tid + off];
        __syncthreads();
    }
    if (tid == 0) part[blockIdx.x] = s[0];
}

__global__ void scan_block(int* __restrict__ part, int nb, int* __restrict__ rowptr,
                           int n, int nE) {
    __shared__ int s[1024];
    int tid = threadIdx.x;
    int v = (tid < nb) ? part[tid] : 0;
    s[tid] = v;
    __syncthreads();
    for (int off = 1; off < 1024; off <<= 1) {
        int t = (tid >= off) ? s[tid - off] : 0;
        __syncthreads();
        s[tid] += t;
        __syncthreads();
    }
    if (tid < nb) part[tid] = s[tid] - v;   // exclusive
    if (tid == 0) rowptr[n] = nE;
}

__global__ void scan_final(const int* __restrict__ cnt, const int* __restrict__ part,
                           int* __restrict__ rowptr, int* __restrict__ cursor,
                           float* __restrict__ dinv, int n) {
    __shared__ int s[256];
    int tid = threadIdx.x;
    int i = blockIdx.x * 256 + tid;
    int c = (i < n) ? cnt[i] : 0;
    s[tid] = c;
    __syncthreads();
    for (int off = 1; off < 256; off <<= 1) {
        int t = (tid >= off) ? s[tid - off] : 0;
        __syncthreads();
        s[tid] += t;
        __syncthreads();
    }
    if (i < n) {
        int ex = s[tid] - c + part[blockIdx.x];
        rowptr[i] = ex;
        cursor[i] = ex;
        dinv[i] = rsqrtf((float)c + 1.0f);
    }
}

// ---------------- fill CSR ----------------
__global__ void fill_kernel(const int* __restrict__ ei, int* __restrict__ cursor,
                            const float* __restrict__ dinv, int* __restrict__ col,
                            float* __restrict__ ens, int nE) {
    int e = blockIdx.x * 256 + threadIdx.x;
    if (e < nE) {
        int s = ei[e];
        int d = ei[nE + e];
        int pos = atomicAdd(&cursor[d], 1);
        col[pos] = s;
        ens[pos] = dinv[s] * dinv[d];
    }
}

// ---------------- GEMM: m = x @ W1 (32->64), f32 in, bf16 out ----------------
__global__ void gemm_in(const float* __restrict__ x, const float* __restrict__ W,
                        u16* __restrict__ m, int n) {
    __shared__ float Ws[DIN * HD];   // 8 KB, [k][f]
    __shared__ float hs[64 * DIN];   // 8 KB, [r][k]
    int tid = threadIdx.x;
    const float4* W4 = (const float4*)W;
    float4* Ws4 = (float4*)Ws;
#pragma unroll
    for (int i = 0; i < 2; ++i) Ws4[tid + 256 * i] = W4[tid + 256 * i];
    int base = blockIdx.x * 64;
    const float4* x4 = (const float4*)(x + (size_t)base * DIN);
    float4* hs4 = (float4*)hs;
#pragma unroll
    for (int i = 0; i < 2; ++i) {
        int q = tid + 256 * i;           // 512 float4; 8 per row
        int r = q >> 3;
        hs4[q] = (base + r < n) ? x4[q] : make_float4(0.f, 0.f, 0.f, 0.f);
    }
    __syncthreads();
    int f = tid & 63, w = tid >> 6;
    for (int r = w * 16; r < w * 16 + 16; ++r) {
        int row = base + r;
        if (row >= n) break;
        const float4* hr4 = (const float4*)&hs[r * DIN];
        float acc = 0.f;
#pragma unroll
        for (int kk = 0; kk < 8; ++kk) {
            float4 hv = hr4[kk];
            acc = fmaf(hv.x, Ws[(kk * 4 + 0) * HD + f], acc);
            acc = fmaf(hv.y, Ws[(kk * 4 + 1) * HD + f], acc);
            acc = fmaf(hv.z, Ws[(kk * 4 + 2) * HD + f], acc);
            acc = fmaf(hv.w, Ws[(kk * 4 + 3) * HD + f], acc);
        }
        m[(size_t)row * HD + f] = f2b(acc);
    }
}

// ---------------- GEMM + fused BN input: m = (h*sc+sh) @ W (64->64), bf16 in/out ----------------
__global__ void gemm_hid(const u16* __restrict__ h, const float* __restrict__ W,
                         const float* __restrict__ stats, const float* __restrict__ g,
                         const float* __restrict__ be, u16* __restrict__ m,
                         int n, float inv_n) {
    __shared__ float Ws[HD * HD];    // 16 KB, [k][f]
    __shared__ float hs[64 * HD];    // 16 KB, [r][k] f32, BN pre-applied
    __shared__ float sc[HD], sh[HD];
    int tid = threadIdx.x;
    if (tid < HD) {
        float mu = stats[tid] * inv_n;
        float var = stats[64 + tid] * inv_n - mu * mu;
        float scv = g[tid] * rsqrtf(var + BN_EPS);
        sc[tid] = scv;
        sh[tid] = be[tid] - mu * scv;
    }
    const float4* W4 = (const float4*)W;
    float4* Ws4 = (float4*)Ws;
#pragma unroll
    for (int i = 0; i < 4; ++i) Ws4[tid + 256 * i] = W4[tid + 256 * i];
    __syncthreads();
    int base = blockIdx.x * 64;
    const uint4* h4 = (const uint4*)(h + (size_t)base * HD);   // 16 B = 8 bf16
#pragma unroll
    for (int i = 0; i < 2; ++i) {
        int q = tid + 256 * i;           // 512 uint4; 8 per row
        int r = q >> 3;
        int c = (q & 7) * 8;
        float v[8];
#pragma unroll
        for (int j = 0; j < 8; ++j) v[j] = 0.f;
        if (base + r < n) {
            uint4 raw = h4[q];
            v[0] = b2f((u16)(raw.x & 0xffff)); v[1] = b2f((u16)(raw.x >> 16));
            v[2] = b2f((u16)(raw.y & 0xffff)); v[3] = b2f((u16)(raw.y >> 16));
            v[4] = b2f((u16)(raw.z & 0xffff)); v[5] = b2f((u16)(raw.z >> 16));
            v[6] = b2f((u16)(raw.w & 0xffff)); v[7] = b2f((u16)(raw.w >> 16));
#pragma unroll
            for (int j = 0; j < 8; ++j) v[j] = fmaf(v[j], sc[c + j], sh[c + j]);
        }
        float* dst = &hs[r * HD + c];
        *(float4*)dst = make_float4(v[0], v[1], v[2], v[3]);
        *(float4*)(dst + 4) = make_float4(v[4], v[5], v[6], v[7]);
    }
    __syncthreads();
    int f = tid & 63, w = tid >> 6;
    for (int r = w * 16; r < w * 16 + 16; ++r) {
        int row = base + r;
        if (row >= n) break;
        const float4* hr4 = (const float4*)&hs[r * HD];
        float acc = 0.f;
#pragma unroll
        for (int kk = 0; kk < 16; ++kk) {
            float4 hv = hr4[kk];
            acc = fmaf(hv.x, Ws[(kk * 4 + 0) * HD + f], acc);
            acc = fmaf(hv.y, Ws[(kk * 4 + 1) * HD + f], acc);
            acc = fmaf(hv.z, Ws[(kk * 4 + 2) * HD + f], acc);
            acc = fmaf(hv.w, Ws[(kk * 4 + 3) * HD + f], acc);
        }
        m[(size_t)row * HD + f] = f2b(acc);
    }
}

// ---------------- fused aggregate (gather) + ReLU + BN stats; bf16 m/h ----------------
// Chunked: block b covers rows [b*64, b*64+64), wave w rows [.. + w*16, +16).
// Dual-row interleave for 2 outstanding gathers per wave.
__global__ void agg_kernel(const u16* __restrict__ m, const int* __restrict__ rowptr,
                           const int* __restrict__ col, const float* __restrict__ ens,
                           const float* __restrict__ dinv, const float* __restrict__ b,
                           u16* __restrict__ h, float* __restrict__ stats, int n) {
    int tid = threadIdx.x;
    int lane = tid & 63;
    int w = tid >> 6;
    int rbeg = blockIdx.x * 64 + w * 16;
    int rend = rbeg + 16; if (rend > n) rend = n;
    float bf = b[lane];
    float s = 0.f, s2 = 0.f;
    for (int i = rbeg; i < rend; i += 2) {
        bool two = (i + 1 < rend);
        int p0 = rowptr[i];
        int e0 = rowptr[i + 1];
        int p1 = e0;
        int e1 = two ? rowptr[i + 2] : e0;
        float d0 = dinv[i];
        float a0 = fmaf(d0 * d0, b2f(m[(size_t)i * HD + lane]), bf);
        float a1 = 0.f;
        if (two) {
            float d1 = dinv[i + 1];
            a1 = fmaf(d1 * d1, b2f(m[(size_t)(i + 1) * HD + lane]), bf);
        }
        while (p0 < e0 && p1 < e1) {
            int s0 = col[p0]; float w0 = ens[p0];
            int s1 = col[p1]; float w1 = ens[p1];
            float v0 = b2f(m[(size_t)s0 * HD + lane]);
            float v1 = b2f(m[(size_t)s1 * HD + lane]);
            a0 = fmaf(w0, v0, a0);
            a1 = fmaf(w1, v1, a1);
            ++p0; ++p1;
        }
        while (p0 < e0) { a0 = fmaf(ens[p0], b2f(m[(size_t)col[p0] * HD + lane]), a0); ++p0; }
        while (p1 < e1) { a1 = fmaf(ens[p1], b2f(m[(size_t)col[p1] * HD + lane]), a1); ++p1; }
        float v = fmaxf(a0, 0.f);
        h[(size_t)i * HD + lane] = f2b(v);
        s += v; s2 += v * v;
        if (two) {
            float u = fmaxf(a1, 0.f);
            h[(size_t)(i + 1) * HD + lane] = f2b(u);
            s += u; s2 += u * u;
        }
    }
    __shared__ float ls[256], ls2[256];
    ls[tid] = s; ls2[tid] = s2;
    __syncthreads();
    if (tid < 64) {
        s = ls[tid] + ls[tid + 64] + ls[tid + 128] + ls[tid + 192];
        s2 = ls2[tid] + ls2[tid + 64] + ls2[tid + 128] + ls2[tid + 192];
        atomicAdd(&stats[tid], s);
        atomicAdd(&stats[64 + tid], s2);
    }
}

// ---------------- final FC + fused BN: out = (h*sc+sh) @ fcW + fcb, bf16 h ----------------
__global__ void fc_kernel(const u16* __restrict__ h, const float* __restrict__ stats,
                          const float* __restrict__ g, const float* __restrict__ be,
                          const float* __restrict__ fcW, const float* __restrict__ fcb,
                          float* __restrict__ out, int n, float inv_n) {
    __shared__ float Ws[HD * DOUT];  // 2 KB, [k][o]
    __shared__ float hs[32 * 68];    // padded stride 68
    __shared__ float sc[HD], sh[HD], bb[DOUT];
    int tid = threadIdx.x;
    if (tid < 128) ((float4*)Ws)[tid] = ((const float4*)fcW)[tid];
    if (tid < HD) {
        float mu = stats[tid] * inv_n;
        float var = stats[64 + tid] * inv_n - mu * mu;
        float scv = g[tid] * rsqrtf(var + BN_EPS);
        sc[tid] = scv;
        sh[tid] = be[tid] - mu * scv;
    }
    if (tid < DOUT) bb[tid] = fcb[tid];
    int base = blockIdx.x * 32;
    const uint4* h4 = (const uint4*)(h + (size_t)base * HD);
    __syncthreads();
    {
        int q = tid;                     // 256 uint4 = 32 rows × 8
        int r = q >> 3;
        int c = (q & 7) * 8;
        float v[8];
#pragma unroll
        for (int j = 0; j < 8; ++j) v[j] = 0.f;
        if (base + r < n) {
            uint4 raw = h4[q];
            v[0] = b2f((u16)(raw.x & 0xffff)); v[1] = b2f((u16)(raw.x >> 16));
            v[2] = b2f((u16)(raw.y & 0xffff)); v[3] = b2f((u16)(raw.y >> 16));
            v[4] = b2f((u16)(raw.z & 0xffff)); v[5] = b2f((u16)(raw.z >> 16));
            v[6] = b2f((u16)(raw.w & 0xffff)); v[7] = b2f((u16)(raw.w >> 16));
#pragma unroll
            for (int j = 0; j < 8; ++j) v[j] = fmaf(v[j], sc[c + j], sh[c + j]);
        }
        float* dst = &hs[r * 68 + c];
        *(float4*)dst = make_float4(v[0], v[1], v[2], v[3]);
        *(float4*)(dst + 4) = make_float4(v[4], v[5], v[6], v[7]);
    }
    __syncthreads();
    int r = tid >> 3, o = tid & 7;
    const float4* hr4 = (const float4*)&hs[r * 68];
    float acc = bb[o];
#pragma unroll
    for (int kk = 0; kk < 16; ++kk) {
        float4 hv = hr4[kk];
        acc = fmaf(hv.x, Ws[(kk * 4 + 0) * DOUT + o], acc);
        acc = fmaf(hv.y, Ws[(kk * 4 + 1) * DOUT + o], acc);
        acc = fmaf(hv.z, Ws[(kk * 4 + 2) * DOUT + o], acc);
        acc = fmaf(hv.w, Ws[(kk * 4 + 3) * DOUT + o], acc);
    }
    if (base + r < n) out[(size_t)(base + r) * DOUT + o] = acc;
}

extern "C" void kernel_launch(void* const* d_in, const int* in_sizes, int n_in,
                              void* d_out, int out_size, void* d_ws, size_t ws_size,
                              hipStream_t stream) {
    const float* x   = (const float*)d_in[0];
    const int*   ei  = (const int*)d_in[1];
    const float* W1  = (const float*)d_in[2];
    const float* b1  = (const float*)d_in[3];
    const float* g1  = (const float*)d_in[4];
    const float* be1 = (const float*)d_in[5];
    const float* W2  = (const float*)d_in[6];
    const float* b2  = (const float*)d_in[7];
    const float* g2  = (const float*)d_in[8];
    const float* be2 = (const float*)d_in[9];
    const float* W3  = (const float*)d_in[10];
    const float* b3  = (const float*)d_in[11];
    const float* g3  = (const float*)d_in[12];
    const float* be3 = (const float*)d_in[13];
    const float* fcW = (const float*)d_in[14];
    const float* fcb = (const float*)d_in[15];
    float* out = (float*)d_out;

    const int n  = in_sizes[0] / DIN;   // 100000
    const int nE = in_sizes[1] / 2;     // 1000000

    char* ws = (char*)d_ws;
    size_t off = 0;
    auto carve = [&](size_t bytes) -> void* {
        void* p = ws + off;
        off = (off + bytes + 255) & ~(size_t)255;
        return p;
    };
    int*   cnt    = (int*)carve((size_t)n * 4);
    int*   rowptr = (int*)carve((size_t)(n + 1) * 4);
    int*   cursor = (int*)carve((size_t)n * 4);
    float* dinv   = (float*)carve((size_t)n * 4);
    int*   part   = (int*)carve(1024 * 4);
    int*   col    = (int*)carve((size_t)nE * 4);
    float* ens    = (float*)carve((size_t)nE * 4);
    u16*   m      = (u16*)carve((size_t)n * HD * 2);   // bf16
    u16*   h      = (u16*)carve((size_t)n * HD * 2);   // bf16
    float* stats  = (float*)carve(3 * 128 * 4);

    const int gEdge = (nE + 255) / 256;
    const int g64   = (n + 63) / 64;    // 1563: gemm AND agg use same tiling
    const int g32   = (n + 31) / 32;
    const int nb    = (n + 255) / 256;
    const float inv_n = 1.0f / (float)n;

    // ---- CSR + norm precompute ----
    hipMemsetAsync(cnt, 0, (size_t)n * 4, stream);
    hipMemsetAsync(stats, 0, 3 * 128 * 4, stream);
    hist_kernel<<<gEdge, 256, 0, stream>>>(ei, cnt, nE);
    scan_partial<<<nb, 256, 0, stream>>>(cnt, part, n);
    scan_block<<<1, 1024, 0, stream>>>(part, nb, rowptr, n, nE);
    scan_final<<<nb, 256, 0, stream>>>(cnt, part, rowptr, cursor, dinv, n);
    fill_kernel<<<gEdge, 256, 0, stream>>>(ei, cursor, dinv, col, ens, nE);

    // ---- layer 1 ----
    gemm_in<<<g64, 256, 0, stream>>>(x, W1, m, n);
    agg_kernel<<<g64, 256, 0, stream>>>(m, rowptr, col, ens, dinv, b1, h, stats, n);

    // ---- layer 2 ----
    gemm_hid<<<g64, 256, 0, stream>>>(h, W2, stats, g1, be1, m, n, inv_n);
    agg_kernel<<<g64, 256, 0, stream>>>(m, rowptr, col, ens, dinv, b2, h, stats + 128, n);

    // ---- layer 3 ----
    gemm_hid<<<g64, 256, 0, stream>>>(h, W3, stats + 128, g2, be2, m, n, inv_n);
    agg_kernel<<<g64, 256, 0, stream>>>(m, rowptr, col, ens, dinv, b3, h, stats + 256, n);

    // ---- final FC ----
    fc_kernel<<<g32, 256, 0, stream>>>(h, stats + 256, g3, be3, fcW, fcb, out, n, inv_n);
}